// Round 1
// baseline (642.903 us; speedup 1.0000x reference)
//
#include <hip/hip_runtime.h>
#include <hip/hip_bf16.h>

#define B 32
#define C_IN 192
#define T 8192
#define H 192
#define N_PH 1024
#define OUT 4
#define ROW_MAX 7168   // max total frames = 7 * 1024

// ---------------- K1: inclusive scan of durations per batch ----------------
__global__ __launch_bounds__(1024) void scan_kernel(const int* __restrict__ w,
                                                    int* __restrict__ ends) {
    int b = blockIdx.x;
    __shared__ int s[N_PH];
    int tid = threadIdx.x;
    s[tid] = w[b * N_PH + tid];
    __syncthreads();
    for (int off = 1; off < N_PH; off <<= 1) {
        int v = (tid >= off) ? s[tid - off] : 0;
        __syncthreads();
        s[tid] += v;
        __syncthreads();
    }
    ends[b * N_PH + tid] = s[tid];
}

// ---------------- K2: segment mean  spec[b,c,j] ----------------
__global__ __launch_bounds__(256) void segmean_kernel(const float* __restrict__ x,
                                                      const int* __restrict__ ends,
                                                      float* __restrict__ spec) {
    int bc = blockIdx.x;
    int b = bc / C_IN;
    int c = bc % C_IN;
    __shared__ int e_s[N_PH];
    __shared__ float row[ROW_MAX];
    int tid = threadIdx.x;
    for (int j = tid; j < N_PH; j += 256) e_s[j] = ends[b * N_PH + j];
    __syncthreads();
    int emax = e_s[N_PH - 1];
    if (emax > ROW_MAX) emax = ROW_MAX;
    const float* xr = x + ((size_t)b * C_IN + c) * T;
    for (int t = tid; t < emax; t += 256) row[t] = xr[t];
    __syncthreads();
    float* sp = spec + ((size_t)b * C_IN + c) * N_PH;
    for (int j = tid; j < N_PH; j += 256) {
        int s0 = j ? e_s[j - 1] : 0;
        int e0 = e_s[j];
        if (s0 > emax) s0 = emax;
        if (e0 > emax) e0 = emax;
        float sum = 0.f;
        for (int t = s0; t < e0; ++t) sum += row[t];
        sp[j] = (e0 > s0) ? sum / (float)(e0 - s0) : 0.f;
    }
}

// ---------------- weight transposes ----------------
__global__ void transpose_pre_kernel(const float* __restrict__ w, float* __restrict__ wt) {
    int i = blockIdx.x * 256 + threadIdx.x;  // over H*C_IN
    if (i < H * C_IN) {
        int h = i / C_IN, c = i % C_IN;
        wt[c * H + h] = w[h * C_IN + c];
    }
}
__global__ void transpose_conv_kernel(const float* __restrict__ w, float* __restrict__ wt) {
    int idx = blockIdx.x * 256 + threadIdx.x;  // over H*H*3
    if (idx < H * H * 3) {
        int o = idx / (H * 3);
        int r = idx % (H * 3);
        int i = r / 3, k = r % 3;
        wt[(i * 3 + k) * H + o] = w[idx];
    }
}

// ---------------- K3: pointwise GEMM h[b,h,t] = pre_w @ spec + pre_b ----------------
// block = (t-tile of 32, batch), 192 threads = one per output channel
__global__ __launch_bounds__(192) void pregemm_kernel(const float* __restrict__ spec,
                                                      const float* __restrict__ wt,
                                                      const float* __restrict__ bias,
                                                      float* __restrict__ out) {
    int b = blockIdx.y;
    int t0 = blockIdx.x * 32;
    __shared__ float tile[C_IN][32];
    int tid = threadIdx.x;
    const float* sb = spec + (size_t)b * C_IN * N_PH + t0;
    for (int idx = tid; idx < C_IN * 32; idx += 192) {
        int c = idx >> 5, tt = idx & 31;
        tile[c][tt] = sb[c * N_PH + tt];
    }
    __syncthreads();
    float acc[32];
    float bv = bias[tid];
#pragma unroll
    for (int t = 0; t < 32; ++t) acc[t] = bv;
    for (int c = 0; c < C_IN; ++c) {
        float wv = wt[c * H + tid];
#pragma unroll
        for (int t = 0; t < 32; ++t) acc[t] += wv * tile[c][t];
    }
    float* ob = out + (size_t)b * H * N_PH + (size_t)tid * N_PH + t0;
#pragma unroll
    for (int t = 0; t < 32; ++t) ob[t] = acc[t];
}

// ---------------- K4: fused  conv3(in*mask) + bias -> relu(*mask) -> LN(*mask) -> *mask ----
__global__ __launch_bounds__(192) void conv_ln_kernel(const float* __restrict__ in,
                                                      const float* __restrict__ wt,
                                                      const float* __restrict__ bias,
                                                      const float* __restrict__ mask,
                                                      const float* __restrict__ g,
                                                      const float* __restrict__ beta,
                                                      float* __restrict__ out) {
    int b = blockIdx.y;
    int t0 = blockIdx.x * 32;
    __shared__ float tile[H][34];
    __shared__ float mstat[32], rstat[32];
    int tid = threadIdx.x;
    const float* ib = in + (size_t)b * H * N_PH;
    const float* mb = mask + b * N_PH;
    for (int idx = tid; idx < H * 34; idx += 192) {
        int c = idx / 34, tt = idx % 34;
        int t = t0 + tt - 1;
        float v = 0.f;
        if (t >= 0 && t < N_PH) v = ib[c * N_PH + t] * mb[t];
        tile[c][tt] = v;
    }
    __syncthreads();
    float acc[32];
    float bv = bias[tid];
#pragma unroll
    for (int t = 0; t < 32; ++t) acc[t] = bv;
    for (int i = 0; i < H; ++i) {
        float w0 = wt[(i * 3 + 0) * H + tid];
        float w1 = wt[(i * 3 + 1) * H + tid];
        float w2 = wt[(i * 3 + 2) * H + tid];
#pragma unroll
        for (int t = 0; t < 32; ++t) {
            acc[t] += w0 * tile[i][t] + w1 * tile[i][t + 1] + w2 * tile[i][t + 2];
        }
    }
    // relu(conv * mask) then * mask -> LN input
#pragma unroll
    for (int t = 0; t < 32; ++t) {
        float m = mb[t0 + t];
        acc[t] = fmaxf(acc[t] * m, 0.f) * m;
    }
    __syncthreads();  // done reading tile for conv
#pragma unroll
    for (int t = 0; t < 32; ++t) tile[tid][t] = acc[t];
    __syncthreads();
    if (tid < 32) {
        float s = 0.f, ss = 0.f;
        for (int o = 0; o < H; ++o) {
            float v = tile[o][tid];
            s += v;
            ss += v * v;
        }
        float m = s / (float)H;
        float var = ss / (float)H - m * m;
        mstat[tid] = m;
        rstat[tid] = rsqrtf(var + 1e-5f);
    }
    __syncthreads();
    float gg = g[tid], bb = beta[tid];
    float* ob = out + (size_t)b * H * N_PH + (size_t)tid * N_PH + t0;
#pragma unroll
    for (int t = 0; t < 32; ++t) {
        float m = mb[t0 + t];
        float y = (acc[t] - mstat[t]) * rstat[t] * gg + bb;
        ob[t] = y * m;
    }
}

// ---------------- K5: final linear (4 x 192) + bias, * mask ----------------
__global__ __launch_bounds__(256) void final_kernel(const float* __restrict__ in,
                                                    const float* __restrict__ lw,
                                                    const float* __restrict__ lb,
                                                    const float* __restrict__ mask,
                                                    float* __restrict__ out) {
    int b = blockIdx.y;
    int t = blockIdx.x * 256 + threadIdx.x;
    __shared__ float w_s[OUT * H];
    for (int i = threadIdx.x; i < OUT * H; i += 256) w_s[i] = lw[i];
    __syncthreads();
    const float* ib = in + (size_t)b * H * N_PH + t;
    float a0 = lb[0], a1 = lb[1], a2 = lb[2], a3 = lb[3];
    for (int h = 0; h < H; ++h) {
        float v = ib[(size_t)h * N_PH];
        a0 += w_s[0 * H + h] * v;
        a1 += w_s[1 * H + h] * v;
        a2 += w_s[2 * H + h] * v;
        a3 += w_s[3 * H + h] * v;
    }
    float m = mask[b * N_PH + t];
    float* ob = out + (size_t)b * OUT * N_PH + t;
    ob[0 * N_PH] = a0 * m;
    ob[1 * N_PH] = a1 * m;
    ob[2 * N_PH] = a2 * m;
    ob[3 * N_PH] = a3 * m;
}

extern "C" void kernel_launch(void* const* d_in, const int* in_sizes, int n_in,
                              void* d_out, int out_size, void* d_ws, size_t ws_size,
                              hipStream_t stream) {
    const float* x      = (const float*)d_in[0];
    const float* x_mask = (const float*)d_in[1];
    const int*   w      = (const int*)d_in[2];
    const float* pre_w  = (const float*)d_in[3];
    const float* pre_b  = (const float*)d_in[4];
    const float* conv0_w = (const float*)d_in[5];
    const float* conv0_b = (const float*)d_in[6];
    const float* ln0_g   = (const float*)d_in[7];
    const float* ln0_b   = (const float*)d_in[8];
    const float* conv1_w = (const float*)d_in[9];
    const float* conv1_b = (const float*)d_in[10];
    const float* ln1_g   = (const float*)d_in[11];
    const float* ln1_b   = (const float*)d_in[12];
    const float* lin_w   = (const float*)d_in[13];
    const float* lin_b   = (const float*)d_in[14];
    float* out = (float*)d_out;

    // workspace layout
    char* ws = (char*)d_ws;
    size_t off = 0;
    int* ends = (int*)(ws + off);          off += (size_t)B * N_PH * sizeof(int);
    float* spec = (float*)(ws + off);      off += (size_t)B * C_IN * N_PH * sizeof(float);
    float* bufA = (float*)(ws + off);      off += (size_t)B * H * N_PH * sizeof(float);
    float* bufB = (float*)(ws + off);      off += (size_t)B * H * N_PH * sizeof(float);
    float* pwt  = (float*)(ws + off);      off += (size_t)C_IN * H * sizeof(float);
    float* w0t  = (float*)(ws + off);      off += (size_t)H * 3 * H * sizeof(float);
    float* w1t  = (float*)(ws + off);      off += (size_t)H * 3 * H * sizeof(float);

    // prep: scan + transposes (independent)
    scan_kernel<<<B, 1024, 0, stream>>>(w, ends);
    transpose_pre_kernel<<<(H * C_IN + 255) / 256, 256, 0, stream>>>(pre_w, pwt);
    transpose_conv_kernel<<<(H * H * 3 + 255) / 256, 256, 0, stream>>>(conv0_w, w0t);
    transpose_conv_kernel<<<(H * H * 3 + 255) / 256, 256, 0, stream>>>(conv1_w, w1t);

    // segment mean
    segmean_kernel<<<B * C_IN, 256, 0, stream>>>(x, ends, spec);

    // pre linear
    dim3 g1(N_PH / 32, B);
    pregemm_kernel<<<g1, 192, 0, stream>>>(spec, pwt, pre_b, bufA);

    // block 0
    conv_ln_kernel<<<g1, 192, 0, stream>>>(bufA, w0t, conv0_b, x_mask, ln0_g, ln0_b, bufB);
    // block 1
    conv_ln_kernel<<<g1, 192, 0, stream>>>(bufB, w1t, conv1_b, x_mask, ln1_g, ln1_b, bufA);

    // final projection
    dim3 g2(N_PH / 256, B);
    final_kernel<<<g2, 256, 0, stream>>>(bufA, lin_w, lin_b, x_mask, out);
}

// Round 4
// 513.096 us; speedup vs baseline: 1.2530x; 1.2530x over previous
//
#include <hip/hip_runtime.h>
#include <hip/hip_bf16.h>

#define B 32
#define C_IN 192
#define T 8192
#define H 192
#define N_PH 1024
#define OUT 4
#define ROW_MAX 7168          // max total frames = 7 * 1024
#define PROWS (N_PH + 2)      // padded rows: t = -1 .. N_PH
#define ROWP (2 * H)          // row pitch: hi plane [0,H), lo plane [H,2H)

typedef __attribute__((ext_vector_type(8))) short short8;
typedef __attribute__((ext_vector_type(4))) float f32x4;
typedef unsigned short ushort_t;

__device__ inline ushort_t f2bf(float f) {
    unsigned u = __builtin_bit_cast(unsigned, f);
    unsigned r = u + 0x7fffu + ((u >> 16) & 1u);   // RNE
    return (ushort_t)(r >> 16);
}
__device__ inline float bf2f(ushort_t h) {
    unsigned u = ((unsigned)h) << 16;
    return __builtin_bit_cast(float, u);
}
// split x into hi+lo bf16 pair (~17-bit effective mantissa)
__device__ inline void split_bf(float x, ushort_t& hi, ushort_t& lo) {
    hi = f2bf(x);
    lo = f2bf(x - bf2f(hi));
}

// ---------------- K1: inclusive scan of durations per batch ----------------
__global__ __launch_bounds__(1024) void scan_kernel(const int* __restrict__ w,
                                                    int* __restrict__ ends) {
    int b = blockIdx.x;
    __shared__ int s[N_PH];
    int tid = threadIdx.x;
    s[tid] = w[b * N_PH + tid];
    __syncthreads();
    for (int off = 1; off < N_PH; off <<= 1) {
        int v = (tid >= off) ? s[tid - off] : 0;
        __syncthreads();
        s[tid] += v;
        __syncthreads();
    }
    ends[b * N_PH + tid] = s[tid];
}

// ---------------- K2: segment mean  spec[b,c,j] (fp32, [b][c][j]) ----------------
__global__ __launch_bounds__(256) void segmean_kernel(const float* __restrict__ x,
                                                      const int* __restrict__ ends,
                                                      float* __restrict__ spec) {
    int bc = blockIdx.x;
    int b = bc / C_IN;
    int c = bc % C_IN;
    __shared__ int e_s[N_PH];
    __shared__ float row[ROW_MAX];
    int tid = threadIdx.x;
    for (int j = tid; j < N_PH; j += 256) e_s[j] = ends[b * N_PH + j];
    __syncthreads();
    int emax = e_s[N_PH - 1];
    if (emax > ROW_MAX) emax = ROW_MAX;
    const float4* xr4 = (const float4*)(x + ((size_t)b * C_IN + c) * T);
    float4* row4 = (float4*)row;
    int nv = (emax + 3) >> 2;   // 4*nv <= ROW_MAX and < T: safe
    for (int t = tid; t < nv; t += 256) row4[t] = xr4[t];
    __syncthreads();
    float* sp = spec + ((size_t)b * C_IN + c) * N_PH;
    for (int j = tid; j < N_PH; j += 256) {
        int s0 = j ? e_s[j - 1] : 0;
        int e0 = e_s[j];
        float sum = 0.f;
        for (int t = s0; t < e0; ++t) sum += row[t];
        sp[j] = (e0 > s0) ? sum / (float)(e0 - s0) : 0.f;
    }
}

// ---------------- transpose spec -> time-major split bf16 [b][j][hi:H|lo:H] -------
__global__ __launch_bounds__(256) void transpose_spec_kernel(const float* __restrict__ spec,
                                                             ushort_t* __restrict__ specT) {
    int jt = blockIdx.x * 32;
    int ct = (blockIdx.y % (C_IN / 32)) * 32;
    int b  = blockIdx.y / (C_IN / 32);
    __shared__ float tile[32][33];
    int tx = threadIdx.x & 31;
    int ty = threadIdx.x >> 5;     // 8 rows per pass
    const float* sb = spec + ((size_t)b * C_IN + ct) * N_PH + jt;
    for (int r = ty; r < 32; r += 8) tile[r][tx] = sb[(size_t)r * N_PH + tx]; // [c_loc][j_loc]
    __syncthreads();
    ushort_t* ob = specT + ((size_t)b * N_PH + jt) * ROWP + ct;
    for (int r = ty; r < 32; r += 8) {
        ushort_t hi, lo;
        split_bf(tile[tx][r], hi, lo);
        ob[(size_t)r * ROWP + tx] = hi;
        ob[(size_t)r * ROWP + H + tx] = lo;
    }
}

// ---------------- weight prep: MFMA-fragment-ordered, split hi/lo ----------------
// Fragment slot (kt, s, nt): 512 ushort = lane*8 + j.
// Stored value: w[o = nt*16 + (lane&15)][k_in_tap = s*32 + (lane>>4)*8 + j][tap kt]
// This is the EXACT (lane,j)->(-o,k) formula the GEMM kernel uses for its A-loads,
// so A/B k-pairing is correct by construction.
__global__ void wfrag_cvt_kernel(const float* __restrict__ w, ushort_t* __restrict__ wtf,
                                 int taps) {
    int idx = blockIdx.x * 256 + threadIdx.x;
    int ntot = taps * 6 * 12 * 512;
    if (idx >= ntot) return;
    int j  = idx & 7;
    int l  = (idx >> 3) & 63;
    int slot = idx >> 9;             // (kt*6 + s)*12 + nt
    int nt = slot % 12;
    int ss = (slot / 12) % 6;
    int kt = slot / 72;
    int o  = nt * 16 + (l & 15);
    int i  = ss * 32 + ((l >> 4) << 3) + j;       // input channel within tap
    float v = (taps == 1) ? w[o * C_IN + i]        // pre_w [h][c]
                          : w[(o * H + i) * 3 + kt]; // conv_w [o][i][k]
    ushort_t hi, lo;
    split_bf(v, hi, lo);
    wtf[idx] = hi;
    wtf[idx + ntot] = lo;
}

// ---------------- fused MFMA GEMM: conv(taps) + bias [+relu+LN] + mask, split out ----
// in: time-major split bf16, row t at in + t*ROWP (negative rows valid for taps=3)
// wt: fragment-ordered (see wfrag_cvt_kernel), hi plane then lo plane
// out: padded [b][PROWS][ROWP], row t at +(t+1)*ROWP
// 16x16x32 MFMA, m97-verified conventions:
//   A: m = lane&15 (time), k = (lane>>4)*8 + j  (bf16x8 contiguous)
//   B: n = lane&15 (channel), same k formula (by converter construction)
//   C/D: col = lane&15 (channel), row = (lane>>4)*4 + reg (time)
__global__ __launch_bounds__(256) void gemm_fused_kernel(
    const ushort_t* __restrict__ in, int in_rows,
    const ushort_t* __restrict__ wt,
    const float* __restrict__ bias,
    const float* __restrict__ mask,
    const float* __restrict__ g, const float* __restrict__ beta,
    ushort_t* __restrict__ out,
    int taps, int do_ln, int nmask)
{
    int b  = blockIdx.y;
    int t0 = blockIdx.x * 64;
    int tid = threadIdx.x;
    int lane = tid & 63;
    int wv = tid >> 6;

    __shared__ float ep[64][193];
    __shared__ float g_s[H], b_s[H], m_s[64], mstat[64], rstat[64];
    if (tid < H) { g_s[tid] = do_ln ? g[tid] : 1.f; b_s[tid] = do_ln ? beta[tid] : 0.f; }
    if (tid < 64) m_s[tid] = mask[b * N_PH + t0 + tid];

    // zero halo rows (t=-1 and t=N_PH), both planes
    short8 z8 = {0, 0, 0, 0, 0, 0, 0, 0};
    if (t0 == 0 && tid < ROWP / 8)
        *(short8*)(out + (size_t)b * PROWS * ROWP + tid * 8) = z8;
    if (t0 == N_PH - 64 && tid < ROWP / 8)
        *(short8*)(out + ((size_t)b * PROWS + N_PH + 1) * ROWP + tid * 8) = z8;

    int m  = lane & 15;                 // A time-row / B channel / D col
    int kg = (lane >> 4) << 3;          // k offset within 32-step: 0,8,16,24
    int ntotw = taps * 36864;           // hi-plane size; lo at +ntotw
    int pad = taps >> 1;

    const ushort_t* inb = in + (size_t)b * in_rows * ROWP;
    int trow = t0 + wv * 16 + m;        // this lane's A time row

    f32x4 acc[12];
#pragma unroll
    for (int nt = 0; nt < 12; ++nt) {
        float bb = bias[nt * 16 + m];
        acc[nt] = (f32x4){bb, bb, bb, bb};
    }

    for (int kt = 0; kt < taps; ++kt) {
        const ushort_t* arow = inb + (long)(trow + kt - pad) * ROWP;
#pragma unroll
        for (int s = 0; s < 6; ++s) {
            int ko = s * 32 + kg;
            short8 ah8 = *(const short8*)(arow + ko);
            short8 al8 = *(const short8*)(arow + H + ko);
            const ushort_t* wbase = wt + ((size_t)((kt * 6 + s) * 12) << 9) + (lane << 3);
#pragma unroll
            for (int nt = 0; nt < 12; ++nt) {
                short8 bh8 = *(const short8*)(wbase + (nt << 9));
                short8 bl8 = *(const short8*)(wbase + (nt << 9) + ntotw);
                // hi*hi + lo*hi + hi*lo  (lo*lo ~ 2^-18, negligible)
                acc[nt] = __builtin_amdgcn_mfma_f32_16x16x32_bf16(ah8, bh8, acc[nt], 0, 0, 0);
                acc[nt] = __builtin_amdgcn_mfma_f32_16x16x32_bf16(al8, bh8, acc[nt], 0, 0, 0);
                acc[nt] = __builtin_amdgcn_mfma_f32_16x16x32_bf16(ah8, bl8, acc[nt], 0, 0, 0);
            }
        }
    }

    __syncthreads();   // covers g_s/b_s/m_s staging

    // write pre-LN (or final-masked) values to LDS, C/D layout -> [time][channel]
    int rbase = (lane >> 4) << 2;
#pragma unroll
    for (int nt = 0; nt < 12; ++nt) {
        int o = nt * 16 + m;
#pragma unroll
        for (int r = 0; r < 4; ++r) {
            int t_loc = wv * 16 + rbase + r;
            float mm = m_s[t_loc];
            float v = acc[nt][r];
            if (do_ln) {
                v = fmaxf(v * mm, 0.f) * mm;     // relu(conv*mask)*mask -> LN input
            } else {
                for (int q = 0; q < nmask; ++q) v *= mm;
            }
            ep[t_loc][o] = v;
        }
    }
    __syncthreads();

    // LN stats: one thread per time row, serial over channels (R1-proven structure)
    if (do_ln && tid < 64) {
        float s = 0.f, ss = 0.f;
        for (int c = 0; c < H; ++c) {
            float v = ep[tid][c];
            s += v;
            ss += v * v;
        }
        float mean = s * (1.f / (float)H);
        mstat[tid] = mean;
        rstat[tid] = rsqrtf(ss * (1.f / (float)H) - mean * mean + 1e-5f);
    }
    __syncthreads();

    // store: 4 threads per row, 48 channels each, split bf16
    int row = tid >> 2;
    int q = tid & 3;
    float mean = 0.f, rstd = 1.f, mfac = 1.f;
    if (do_ln) {
        mean = mstat[row];
        rstd = rstat[row];
        float mk = m_s[row];
        mfac = (nmask == 2) ? mk * mk : mk;
    }
    ushort_t* orow = out + ((size_t)b * PROWS + t0 + row + 1) * ROWP + q * 48;
#pragma unroll
    for (int i0 = 0; i0 < 48; i0 += 8) {
        ushort_t th[8], tl[8];
#pragma unroll
        for (int k2 = 0; k2 < 8; ++k2) {
            int c = q * 48 + i0 + k2;
            float v = ep[row][c];
            float y = do_ln ? ((v - mean) * rstd * g_s[c] + b_s[c]) * mfac : v;
            split_bf(y, th[k2], tl[k2]);
        }
        *(short8*)(orow + i0) = *(short8*)th;
        *(short8*)(orow + H + i0) = *(short8*)tl;
    }
}

// ---------------- K5: final linear (4 x 192) + bias, * mask ----------------
__global__ __launch_bounds__(256) void final_kernel(const ushort_t* __restrict__ in,
                                                    const float* __restrict__ lw,
                                                    const float* __restrict__ lb,
                                                    const float* __restrict__ mask,
                                                    float* __restrict__ out) {
    int b = blockIdx.y;
    int t = blockIdx.x * 256 + threadIdx.x;
    __shared__ float w_s[OUT * H];
    for (int i = threadIdx.x; i < OUT * H; i += 256) w_s[i] = lw[i];
    __syncthreads();
    const ushort_t* ib = in + ((size_t)b * PROWS + t + 1) * ROWP;
    float a0 = lb[0], a1 = lb[1], a2 = lb[2], a3 = lb[3];
    for (int h8 = 0; h8 < H / 8; ++h8) {
        short8 vh = *(const short8*)(ib + h8 * 8);
        short8 vl = *(const short8*)(ib + H + h8 * 8);
#pragma unroll
        for (int k = 0; k < 8; ++k) {
            int h = h8 * 8 + k;
            float v = bf2f((ushort_t)vh[k]) + bf2f((ushort_t)vl[k]);
            a0 += w_s[0 * H + h] * v;
            a1 += w_s[1 * H + h] * v;
            a2 += w_s[2 * H + h] * v;
            a3 += w_s[3 * H + h] * v;
        }
    }
    float m = mask[b * N_PH + t];
    float* ob = out + ((size_t)b * OUT) * N_PH + t;
    ob[0 * N_PH] = a0 * m;
    ob[1 * N_PH] = a1 * m;
    ob[2 * N_PH] = a2 * m;
    ob[3 * N_PH] = a3 * m;
}

extern "C" void kernel_launch(void* const* d_in, const int* in_sizes, int n_in,
                              void* d_out, int out_size, void* d_ws, size_t ws_size,
                              hipStream_t stream) {
    const float* x      = (const float*)d_in[0];
    const float* x_mask = (const float*)d_in[1];
    const int*   w      = (const int*)d_in[2];
    const float* pre_w  = (const float*)d_in[3];
    const float* pre_b  = (const float*)d_in[4];
    const float* conv0_w = (const float*)d_in[5];
    const float* conv0_b = (const float*)d_in[6];
    const float* ln0_g   = (const float*)d_in[7];
    const float* ln0_b   = (const float*)d_in[8];
    const float* conv1_w = (const float*)d_in[9];
    const float* conv1_b = (const float*)d_in[10];
    const float* ln1_g   = (const float*)d_in[11];
    const float* ln1_b   = (const float*)d_in[12];
    const float* lin_w   = (const float*)d_in[13];
    const float* lin_b   = (const float*)d_in[14];
    float* out = (float*)d_out;

    // workspace layout
    char* ws = (char*)d_ws;
    size_t off = 0;
    int* ends = (int*)(ws + off);           off += (size_t)B * N_PH * sizeof(int);
    float* spec = (float*)(ws + off);       off += (size_t)B * C_IN * N_PH * sizeof(float);
    ushort_t* bufA = (ushort_t*)(ws + off); off += (size_t)B * PROWS * ROWP * sizeof(ushort_t);
    ushort_t* bufB = (ushort_t*)(ws + off); off += (size_t)B * PROWS * ROWP * sizeof(ushort_t);
    ushort_t* wpre = (ushort_t*)(ws + off); off += (size_t)2 * 36864 * sizeof(ushort_t);
    ushort_t* w0t  = (ushort_t*)(ws + off); off += (size_t)2 * 110592 * sizeof(ushort_t);
    ushort_t* w1t  = (ushort_t*)(ws + off); off += (size_t)2 * 110592 * sizeof(ushort_t);
    // specT aliases bufB: consumed by pregemm before conv0 first writes bufB
    ushort_t* specT = bufB;

    // prep (independent)
    scan_kernel<<<B, 1024, 0, stream>>>(w, ends);
    wfrag_cvt_kernel<<<(36864 + 255) / 256, 256, 0, stream>>>(pre_w, wpre, 1);
    wfrag_cvt_kernel<<<(110592 + 255) / 256, 256, 0, stream>>>(conv0_w, w0t, 3);
    wfrag_cvt_kernel<<<(110592 + 255) / 256, 256, 0, stream>>>(conv1_w, w1t, 3);

    // segment mean + transpose to time-major split bf16
    segmean_kernel<<<B * C_IN, 256, 0, stream>>>(x, ends, spec);
    dim3 gt(N_PH / 32, (C_IN / 32) * B);
    transpose_spec_kernel<<<gt, 256, 0, stream>>>(spec, specT);

    dim3 gg(N_PH / 64, B);
    // pre linear: specT (pitch N_PH rows) -> bufA (mask applied for conv0 input)
    gemm_fused_kernel<<<gg, 256, 0, stream>>>(specT, N_PH, wpre, pre_b, x_mask,
                                              ln0_g, ln0_b, bufA, 1, 0, 1);
    // block 0: bufA -> bufB  (out = ln0*mask, + conv1's leading mask)
    gemm_fused_kernel<<<gg, 256, 0, stream>>>(bufA + ROWP, PROWS, w0t, conv0_b, x_mask,
                                              ln0_g, ln0_b, bufB, 3, 1, 2);
    // block 1: bufB -> bufA  (out = ln1*mask)
    gemm_fused_kernel<<<gg, 256, 0, stream>>>(bufB + ROWP, PROWS, w1t, conv1_b, x_mask,
                                              ln1_g, ln1_b, bufA, 3, 1, 1);

    // final projection
    dim3 gf(N_PH / 256, B);
    final_kernel<<<gf, 256, 0, stream>>>(bufA, lin_w, lin_b, x_mask, out);
}

// Round 5
// 419.905 us; speedup vs baseline: 1.5311x; 1.2219x over previous
//
#include <hip/hip_runtime.h>
#include <hip/hip_bf16.h>

#define B 32
#define C_IN 192
#define T 8192
#define H 192
#define N_PH 1024
#define OUT 4
#define ROW_MAX 7168          // max total frames = 7 * 1024
#define PROWS (N_PH + 2)      // padded rows: t = -1 .. N_PH
#define ROWP (2 * H)          // row pitch: hi plane [0,H), lo plane [H,2H)

typedef __attribute__((ext_vector_type(8))) short short8;
typedef __attribute__((ext_vector_type(4))) float f32x4;
typedef unsigned short ushort_t;

__device__ inline ushort_t f2bf(float f) {
    unsigned u = __builtin_bit_cast(unsigned, f);
    unsigned r = u + 0x7fffu + ((u >> 16) & 1u);   // RNE
    return (ushort_t)(r >> 16);
}
__device__ inline float bf2f(ushort_t h) {
    unsigned u = ((unsigned)h) << 16;
    return __builtin_bit_cast(float, u);
}
// split x into hi+lo bf16 pair (~17-bit effective mantissa)
__device__ inline void split_bf(float x, ushort_t& hi, ushort_t& lo) {
    hi = f2bf(x);
    lo = f2bf(x - bf2f(hi));
}

// ---------------- K1: inclusive scan of durations per batch ----------------
__global__ __launch_bounds__(1024) void scan_kernel(const int* __restrict__ w,
                                                    int* __restrict__ ends) {
    int b = blockIdx.x;
    __shared__ int s[N_PH];
    int tid = threadIdx.x;
    s[tid] = w[b * N_PH + tid];
    __syncthreads();
    for (int off = 1; off < N_PH; off <<= 1) {
        int v = (tid >= off) ? s[tid - off] : 0;
        __syncthreads();
        s[tid] += v;
        __syncthreads();
    }
    ends[b * N_PH + tid] = s[tid];
}

// ---------------- K2: segment mean  spec[b,c,j] (fp32, [b][c][j]) ----------------
__global__ __launch_bounds__(256) void segmean_kernel(const float* __restrict__ x,
                                                      const int* __restrict__ ends,
                                                      float* __restrict__ spec) {
    int bc = blockIdx.x;
    int b = bc / C_IN;
    int c = bc % C_IN;
    __shared__ int e_s[N_PH];
    __shared__ float row[ROW_MAX];
    int tid = threadIdx.x;
    for (int j = tid; j < N_PH; j += 256) e_s[j] = ends[b * N_PH + j];
    __syncthreads();
    int emax = e_s[N_PH - 1];
    if (emax > ROW_MAX) emax = ROW_MAX;
    const float4* xr4 = (const float4*)(x + ((size_t)b * C_IN + c) * T);
    float4* row4 = (float4*)row;
    int nv = (emax + 3) >> 2;   // 4*nv <= ROW_MAX and < T: safe
    for (int t = tid; t < nv; t += 256) row4[t] = xr4[t];
    __syncthreads();
    float* sp = spec + ((size_t)b * C_IN + c) * N_PH;
    for (int j = tid; j < N_PH; j += 256) {
        int s0 = j ? e_s[j - 1] : 0;
        int e0 = e_s[j];
        float sum = 0.f;
        for (int t = s0; t < e0; ++t) sum += row[t];
        sp[j] = (e0 > s0) ? sum / (float)(e0 - s0) : 0.f;
    }
}

// ---------------- transpose spec -> time-major split bf16 [b][j][hi:H|lo:H] -------
__global__ __launch_bounds__(256) void transpose_spec_kernel(const float* __restrict__ spec,
                                                             ushort_t* __restrict__ specT) {
    int jt = blockIdx.x * 32;
    int ct = (blockIdx.y % (C_IN / 32)) * 32;
    int b  = blockIdx.y / (C_IN / 32);
    __shared__ float tile[32][33];
    int tx = threadIdx.x & 31;
    int ty = threadIdx.x >> 5;     // 8 rows per pass
    const float* sb = spec + ((size_t)b * C_IN + ct) * N_PH + jt;
    for (int r = ty; r < 32; r += 8) tile[r][tx] = sb[(size_t)r * N_PH + tx]; // [c_loc][j_loc]
    __syncthreads();
    ushort_t* ob = specT + ((size_t)b * N_PH + jt) * ROWP + ct;
    for (int r = ty; r < 32; r += 8) {
        ushort_t hi, lo;
        split_bf(tile[tx][r], hi, lo);
        ob[(size_t)r * ROWP + tx] = hi;
        ob[(size_t)r * ROWP + H + tx] = lo;
    }
}

// ---------------- weight prep: MFMA-fragment-ordered, split hi/lo (R4-proven) -----
// Fragment slot (kt, s, nt): 512 ushort = lane*8 + j.
// Stored value: w[o = nt*16 + (lane&15)][k_in_tap = s*32 + (lane>>4)*8 + j][tap kt]
__global__ void wfrag_cvt_kernel(const float* __restrict__ w, ushort_t* __restrict__ wtf,
                                 int taps) {
    int idx = blockIdx.x * 256 + threadIdx.x;
    int ntot = taps * 6 * 12 * 512;
    if (idx >= ntot) return;
    int j  = idx & 7;
    int l  = (idx >> 3) & 63;
    int slot = idx >> 9;             // (kt*6 + s)*12 + nt
    int nt = slot % 12;
    int ss = (slot / 12) % 6;
    int kt = slot / 72;
    int o  = nt * 16 + (l & 15);
    int i  = ss * 32 + ((l >> 4) << 3) + j;       // input channel within tap
    float v = (taps == 1) ? w[o * C_IN + i]        // pre_w [h][c]
                          : w[(o * H + i) * 3 + kt]; // conv_w [o][i][k]
    ushort_t hi, lo;
    split_bf(v, hi, lo);
    wtf[idx] = hi;
    wtf[idx + ntot] = lo;
}

// ---------------- fused MFMA GEMM: conv(taps) + bias [+relu+LN] + mask, split out ----
// in: time-major split bf16, row t at in + t*ROWP (negative rows valid for taps=3)
// wt: fragment-ordered (see wfrag_cvt_kernel), hi plane then lo plane
// out: padded [b][PROWS][ROWP], row t at +(t+1)*ROWP
// 16x16x32 MFMA, R4-proven conventions:
//   A: m = lane&15 (time), k = (lane>>4)*8 + j  (bf16x8 contiguous)
//   B: n = lane&15 (channel), same k formula (converter-constructed)
//   C/D: col = lane&15 (channel), row = (lane>>4)*4 + reg (time)
// Wave split: wv = mhalf | (nhalf<<1); each wave: 2 A-frags (rows +0/+16),
// 6 n-tiles (nhalf*6..+5). Halves weight-load redundancy vs R4; acc = 48 VGPRs.
__global__ __launch_bounds__(256) void gemm_fused_kernel(
    const ushort_t* __restrict__ in, int in_rows,
    const ushort_t* __restrict__ wt,
    const float* __restrict__ bias,
    const float* __restrict__ mask,
    const float* __restrict__ g, const float* __restrict__ beta,
    ushort_t* __restrict__ out,
    int taps, int do_ln, int nmask)
{
    int b  = blockIdx.y;
    int t0 = blockIdx.x * 64;
    int tid = threadIdx.x;
    int lane = tid & 63;
    int wv = tid >> 6;
    int mhalf = wv & 1;
    int nhalf = wv >> 1;

    __shared__ float ep[64][193];
    __shared__ float g_s[H], b_s[H], m_s[64], mstat[64], rstat[64];
    if (tid < H) { g_s[tid] = do_ln ? g[tid] : 1.f; b_s[tid] = do_ln ? beta[tid] : 0.f; }
    if (tid < 64) m_s[tid] = mask[b * N_PH + t0 + tid];

    // zero halo rows (t=-1 and t=N_PH), both planes
    short8 z8 = {0, 0, 0, 0, 0, 0, 0, 0};
    if (t0 == 0 && tid < ROWP / 8)
        *(short8*)(out + (size_t)b * PROWS * ROWP + tid * 8) = z8;
    if (t0 == N_PH - 64 && tid < ROWP / 8)
        *(short8*)(out + ((size_t)b * PROWS + N_PH + 1) * ROWP + tid * 8) = z8;

    int m  = lane & 15;                 // A time-row / B channel / D col
    int kg = (lane >> 4) << 3;          // k offset within 32-step: 0,8,16,24
    int ntotw = taps * 36864;           // hi-plane size; lo at +ntotw
    int pad = taps >> 1;

    const ushort_t* inb = in + (size_t)b * in_rows * ROWP;
    int trow = t0 + mhalf * 32 + m;     // +16 for second A-frag

    f32x4 acc[2][6];
#pragma unroll
    for (int ntl = 0; ntl < 6; ++ntl) {
        float bb = bias[(nhalf * 6 + ntl) * 16 + m];
        acc[0][ntl] = (f32x4){bb, bb, bb, bb};
        acc[1][ntl] = (f32x4){bb, bb, bb, bb};
    }

#pragma unroll 1
    for (int kt = 0; kt < taps; ++kt) {
        const ushort_t* arow = inb + (long)(trow + kt - pad) * ROWP;
#pragma unroll 1
        for (int s = 0; s < 6; ++s) {
            int ko = s * 32 + kg;
            short8 ah0 = *(const short8*)(arow + ko);
            short8 al0 = *(const short8*)(arow + H + ko);
            short8 ah1 = *(const short8*)(arow + 16 * ROWP + ko);
            short8 al1 = *(const short8*)(arow + 16 * ROWP + H + ko);
            const ushort_t* wbase = wt + ((size_t)((kt * 6 + s) * 12 + nhalf * 6) << 9)
                                  + (lane << 3);
#pragma unroll
            for (int ntl = 0; ntl < 6; ++ntl) {
                short8 bh8 = *(const short8*)(wbase + (ntl << 9));
                short8 bl8 = *(const short8*)(wbase + (ntl << 9) + ntotw);
                // hi*hi + lo*hi + hi*lo  (lo*lo ~ 2^-18, negligible)
                acc[0][ntl] = __builtin_amdgcn_mfma_f32_16x16x32_bf16(ah0, bh8, acc[0][ntl], 0, 0, 0);
                acc[0][ntl] = __builtin_amdgcn_mfma_f32_16x16x32_bf16(al0, bh8, acc[0][ntl], 0, 0, 0);
                acc[0][ntl] = __builtin_amdgcn_mfma_f32_16x16x32_bf16(ah0, bl8, acc[0][ntl], 0, 0, 0);
                acc[1][ntl] = __builtin_amdgcn_mfma_f32_16x16x32_bf16(ah1, bh8, acc[1][ntl], 0, 0, 0);
                acc[1][ntl] = __builtin_amdgcn_mfma_f32_16x16x32_bf16(al1, bh8, acc[1][ntl], 0, 0, 0);
                acc[1][ntl] = __builtin_amdgcn_mfma_f32_16x16x32_bf16(ah1, bl8, acc[1][ntl], 0, 0, 0);
            }
        }
    }

    __syncthreads();   // covers g_s/b_s/m_s staging

    // write pre-LN (or final-masked) values to LDS, C/D layout -> [time][channel]
    int rbase = (lane >> 4) << 2;
#pragma unroll
    for (int mh = 0; mh < 2; ++mh) {
#pragma unroll
        for (int ntl = 0; ntl < 6; ++ntl) {
            int o = (nhalf * 6 + ntl) * 16 + m;
#pragma unroll
            for (int r = 0; r < 4; ++r) {
                int t_loc = mhalf * 32 + mh * 16 + rbase + r;
                float mm = m_s[t_loc];
                float v = acc[mh][ntl][r];
                if (do_ln) {
                    v = fmaxf(v * mm, 0.f) * mm;     // relu(conv*mask)*mask -> LN input
                } else {
                    for (int q = 0; q < nmask; ++q) v *= mm;
                }
                ep[t_loc][o] = v;
            }
        }
    }
    __syncthreads();

    // LN stats: one thread per time row, serial over channels (R4-proven; scalar
    // reads only -- ep row pitch 193 floats is NOT 16B aligned, no float4 here)
    if (do_ln && tid < 64) {
        float s = 0.f, ss = 0.f;
        for (int c = 0; c < H; ++c) {
            float v = ep[tid][c];
            s += v;
            ss += v * v;
        }
        float mean = s * (1.f / (float)H);
        mstat[tid] = mean;
        rstat[tid] = rsqrtf(ss * (1.f / (float)H) - mean * mean + 1e-5f);
    }
    __syncthreads();

    // store: 4 threads per row, 48 channels each, split bf16
    int row = tid >> 2;
    int q = tid & 3;
    float mean = 0.f, rstd = 1.f, mfac = 1.f;
    if (do_ln) {
        mean = mstat[row];
        rstd = rstat[row];
        float mk = m_s[row];
        mfac = (nmask == 2) ? mk * mk : mk;
    }
    ushort_t* orow = out + ((size_t)b * PROWS + t0 + row + 1) * ROWP + q * 48;
#pragma unroll
    for (int i0 = 0; i0 < 48; i0 += 8) {
        ushort_t th[8], tl[8];
#pragma unroll
        for (int k2 = 0; k2 < 8; ++k2) {
            int c = q * 48 + i0 + k2;
            float v = ep[row][c];
            float y = do_ln ? ((v - mean) * rstd * g_s[c] + b_s[c]) * mfac : v;
            split_bf(y, th[k2], tl[k2]);
        }
        *(short8*)(orow + i0) = *(short8*)th;
        *(short8*)(orow + H + i0) = *(short8*)tl;
    }
}

// ---------------- K5: final linear (4 x 192) + bias, * mask (LDS-staged) ----------
__global__ __launch_bounds__(256) void final_kernel(const ushort_t* __restrict__ in,
                                                    const float* __restrict__ lw,
                                                    const float* __restrict__ lb,
                                                    const float* __restrict__ mask,
                                                    float* __restrict__ out) {
    int b = blockIdx.y;
    int t0 = blockIdx.x * 64;
    __shared__ ushort_t s_in[64 * ROWP];       // 48 KB, 64 rows contiguous
    __shared__ float w_s[OUT][H];
    int tid = threadIdx.x;
    for (int i = tid; i < OUT * H; i += 256) w_s[i / H][i % H] = lw[i];
    const short8* g8 = (const short8*)(in + ((size_t)b * PROWS + t0 + 1) * ROWP);
    short8* s8 = (short8*)s_in;
    for (int i = tid; i < 64 * ROWP / 8; i += 256) s8[i] = g8[i];   // coalesced
    __syncthreads();
    int row = tid >> 2;
    int q = tid & 3;
    const ushort_t* rp = s_in + row * ROWP + q * 48;
    float a0 = 0.f, a1 = 0.f, a2 = 0.f, a3 = 0.f;
#pragma unroll
    for (int i0 = 0; i0 < 48; i0 += 8) {
        short8 vh = *(const short8*)(rp + i0);       // 16B-aligned: 96|i0*2, 768|row pitch
        short8 vl = *(const short8*)(rp + H + i0);
#pragma unroll
        for (int k = 0; k < 8; ++k) {
            int c = q * 48 + i0 + k;
            float v = bf2f((ushort_t)vh[k]) + bf2f((ushort_t)vl[k]);
            a0 += w_s[0][c] * v;
            a1 += w_s[1][c] * v;
            a2 += w_s[2][c] * v;
            a3 += w_s[3][c] * v;
        }
    }
    a0 += __shfl_xor(a0, 1); a0 += __shfl_xor(a0, 2);
    a1 += __shfl_xor(a1, 1); a1 += __shfl_xor(a1, 2);
    a2 += __shfl_xor(a2, 1); a2 += __shfl_xor(a2, 2);
    a3 += __shfl_xor(a3, 1); a3 += __shfl_xor(a3, 2);
    if (q == 0) {
        int t = t0 + row;
        float m = mask[b * N_PH + t];
        float* ob = out + (size_t)b * OUT * N_PH + t;
        ob[0 * N_PH] = (a0 + lb[0]) * m;
        ob[1 * N_PH] = (a1 + lb[1]) * m;
        ob[2 * N_PH] = (a2 + lb[2]) * m;
        ob[3 * N_PH] = (a3 + lb[3]) * m;
    }
}

extern "C" void kernel_launch(void* const* d_in, const int* in_sizes, int n_in,
                              void* d_out, int out_size, void* d_ws, size_t ws_size,
                              hipStream_t stream) {
    const float* x      = (const float*)d_in[0];
    const float* x_mask = (const float*)d_in[1];
    const int*   w      = (const int*)d_in[2];
    const float* pre_w  = (const float*)d_in[3];
    const float* pre_b  = (const float*)d_in[4];
    const float* conv0_w = (const float*)d_in[5];
    const float* conv0_b = (const float*)d_in[6];
    const float* ln0_g   = (const float*)d_in[7];
    const float* ln0_b   = (const float*)d_in[8];
    const float* conv1_w = (const float*)d_in[9];
    const float* conv1_b = (const float*)d_in[10];
    const float* ln1_g   = (const float*)d_in[11];
    const float* ln1_b   = (const float*)d_in[12];
    const float* lin_w   = (const float*)d_in[13];
    const float* lin_b   = (const float*)d_in[14];
    float* out = (float*)d_out;

    // workspace layout
    char* ws = (char*)d_ws;
    size_t off = 0;
    int* ends = (int*)(ws + off);           off += (size_t)B * N_PH * sizeof(int);
    float* spec = (float*)(ws + off);       off += (size_t)B * C_IN * N_PH * sizeof(float);
    ushort_t* bufA = (ushort_t*)(ws + off); off += (size_t)B * PROWS * ROWP * sizeof(ushort_t);
    ushort_t* bufB = (ushort_t*)(ws + off); off += (size_t)B * PROWS * ROWP * sizeof(ushort_t);
    ushort_t* wpre = (ushort_t*)(ws + off); off += (size_t)2 * 36864 * sizeof(ushort_t);
    ushort_t* w0t  = (ushort_t*)(ws + off); off += (size_t)2 * 110592 * sizeof(ushort_t);
    ushort_t* w1t  = (ushort_t*)(ws + off); off += (size_t)2 * 110592 * sizeof(ushort_t);
    // specT aliases bufB: consumed by pregemm before conv0 first writes bufB
    ushort_t* specT = bufB;

    // prep (independent)
    scan_kernel<<<B, 1024, 0, stream>>>(w, ends);
    wfrag_cvt_kernel<<<(36864 + 255) / 256, 256, 0, stream>>>(pre_w, wpre, 1);
    wfrag_cvt_kernel<<<(110592 + 255) / 256, 256, 0, stream>>>(conv0_w, w0t, 3);
    wfrag_cvt_kernel<<<(110592 + 255) / 256, 256, 0, stream>>>(conv1_w, w1t, 3);

    // segment mean + transpose to time-major split bf16
    segmean_kernel<<<B * C_IN, 256, 0, stream>>>(x, ends, spec);
    dim3 gt(N_PH / 32, (C_IN / 32) * B);
    transpose_spec_kernel<<<gt, 256, 0, stream>>>(spec, specT);

    dim3 gg(N_PH / 64, B);
    // pre linear: specT (pitch N_PH rows) -> bufA (mask applied for conv0 input)
    gemm_fused_kernel<<<gg, 256, 0, stream>>>(specT, N_PH, wpre, pre_b, x_mask,
                                              ln0_g, ln0_b, bufA, 1, 0, 1);
    // block 0: bufA -> bufB  (out = ln0*mask, + conv1's leading mask)
    gemm_fused_kernel<<<gg, 256, 0, stream>>>(bufA + ROWP, PROWS, w0t, conv0_b, x_mask,
                                              ln0_g, ln0_b, bufB, 3, 1, 2);
    // block 1: bufB -> bufA  (out = ln1*mask)
    gemm_fused_kernel<<<gg, 256, 0, stream>>>(bufB + ROWP, PROWS, w1t, conv1_b, x_mask,
                                              ln1_g, ln1_b, bufA, 3, 1, 1);

    // final projection
    dim3 gf(N_PH / 64, B);
    final_kernel<<<gf, 256, 0, stream>>>(bufA, lin_w, lin_b, x_mask, out);
}

// Round 6
// 397.566 us; speedup vs baseline: 1.6171x; 1.0562x over previous
//
#include <hip/hip_runtime.h>
#include <hip/hip_bf16.h>

#define B 32
#define C_IN 192
#define T 8192
#define H 192
#define N_PH 1024
#define OUT 4
#define ROW_MAX 7168          // max total frames = 7 * 1024
#define PROWS (N_PH + 2)      // padded rows: t = -1 .. N_PH
#define ROWP (2 * H)          // row pitch: hi plane [0,H), lo plane [H,2H)

typedef __attribute__((ext_vector_type(8))) short short8;
typedef __attribute__((ext_vector_type(4))) float f32x4;
typedef unsigned short ushort_t;

__device__ inline ushort_t f2bf(float f) {
    unsigned u = __builtin_bit_cast(unsigned, f);
    unsigned r = u + 0x7fffu + ((u >> 16) & 1u);   // RNE
    return (ushort_t)(r >> 16);
}
__device__ inline float bf2f(ushort_t h) {
    unsigned u = ((unsigned)h) << 16;
    return __builtin_bit_cast(float, u);
}
// split x into hi+lo bf16 pair (~17-bit effective mantissa) -- accuracy-mandatory
__device__ inline void split_bf(float x, ushort_t& hi, ushort_t& lo) {
    hi = f2bf(x);
    lo = f2bf(x - bf2f(hi));
}

// ---------------- K2: segment mean with inline duration scan ----------------
__global__ __launch_bounds__(256) void segmean_kernel(const float* __restrict__ x,
                                                      const int* __restrict__ wdur,
                                                      float* __restrict__ spec) {
    int bc = blockIdx.x;
    int b = bc / C_IN;
    int c = bc % C_IN;
    __shared__ int e_s[N_PH];
    __shared__ int part[256];
    __shared__ float row[ROW_MAX];
    int tid = threadIdx.x;
    // inline inclusive scan of w[b][:] (1024 ints, 4/thread)
    int4 w4 = ((const int4*)(wdur + b * N_PH))[tid];
    int c0 = w4.x, c1 = c0 + w4.y, c2 = c1 + w4.z, c3 = c2 + w4.w;
    part[tid] = c3;
    __syncthreads();
    for (int off = 1; off < 256; off <<= 1) {
        int v = (tid >= off) ? part[tid - off] : 0;
        __syncthreads();
        part[tid] += v;
        __syncthreads();
    }
    int pre = tid ? part[tid - 1] : 0;
    e_s[4 * tid + 0] = pre + c0;
    e_s[4 * tid + 1] = pre + c1;
    e_s[4 * tid + 2] = pre + c2;
    e_s[4 * tid + 3] = pre + c3;
    __syncthreads();
    int emax = e_s[N_PH - 1];           // <= ROW_MAX by construction (w < 8)
    const float4* xr4 = (const float4*)(x + ((size_t)b * C_IN + c) * T);
    float4* row4 = (float4*)row;
    int nv = (emax + 3) >> 2;
    for (int t = tid; t < nv; t += 256) row4[t] = xr4[t];
    __syncthreads();
    float* sp = spec + ((size_t)b * C_IN + c) * N_PH;
    for (int j = tid; j < N_PH; j += 256) {
        int s0 = j ? e_s[j - 1] : 0;
        int e0 = e_s[j];
        float sum = 0.f;
        for (int t = s0; t < e0; ++t) sum += row[t];
        sp[j] = (e0 > s0) ? sum / (float)(e0 - s0) : 0.f;
    }
}

// ---------------- transpose spec -> time-major split bf16 [b][j][hi:H|lo:H] -------
__global__ __launch_bounds__(256) void transpose_spec_kernel(const float* __restrict__ spec,
                                                             ushort_t* __restrict__ specT) {
    int jt = blockIdx.x * 32;
    int ct = (blockIdx.y % (C_IN / 32)) * 32;
    int b  = blockIdx.y / (C_IN / 32);
    __shared__ float tile[32][33];
    int tx = threadIdx.x & 31;
    int ty = threadIdx.x >> 5;     // 8 rows per pass
    const float* sb = spec + ((size_t)b * C_IN + ct) * N_PH + jt;
    for (int r = ty; r < 32; r += 8) tile[r][tx] = sb[(size_t)r * N_PH + tx]; // [c_loc][j_loc]
    __syncthreads();
    ushort_t* ob = specT + ((size_t)b * N_PH + jt) * ROWP + ct;
    for (int r = ty; r < 32; r += 8) {
        ushort_t hi, lo;
        split_bf(tile[tx][r], hi, lo);
        ob[(size_t)r * ROWP + tx] = hi;
        ob[(size_t)r * ROWP + H + tx] = lo;
    }
}

// ---------------- weight prep: MFMA-fragment-ordered, split hi/lo (R4-proven) -----
// Fragment slot (kt, s, nt): 512 ushort = lane*8 + j.
// Stored value: w[o = nt*16 + (lane&15)][k_in_tap = s*32 + (lane>>4)*8 + j][tap kt]
__device__ inline void wfrag_one(const float* __restrict__ w, ushort_t* __restrict__ wtf,
                                 int taps, int idx, int ntot) {
    int j  = idx & 7;
    int l  = (idx >> 3) & 63;
    int slot = idx >> 9;             // (kt*6 + s)*12 + nt
    int nt = slot % 12;
    int ss = (slot / 12) % 6;
    int kt = slot / 72;
    int o  = nt * 16 + (l & 15);
    int i  = ss * 32 + ((l >> 4) << 3) + j;
    float v = (taps == 1) ? w[o * C_IN + i] : w[(o * H + i) * 3 + kt];
    ushort_t hi, lo;
    split_bf(v, hi, lo);
    wtf[idx] = hi;
    wtf[idx + ntot] = lo;
}
__global__ void wfrag_all_kernel(const float* __restrict__ pw, const float* __restrict__ w0,
                                 const float* __restrict__ w1,
                                 ushort_t* __restrict__ wpre, ushort_t* __restrict__ w0t,
                                 ushort_t* __restrict__ w1t) {
    int idx = blockIdx.x * 256 + threadIdx.x;
    const int n1 = 36864, n3 = 110592;
    if (idx < n1) { wfrag_one(pw, wpre, 1, idx, n1); return; }
    idx -= n1;
    if (idx < n3) { wfrag_one(w0, w0t, 3, idx, n3); return; }
    idx -= n3;
    if (idx < n3) wfrag_one(w1, w1t, 3, idx, n3);
}

// ---------------- fused MFMA GEMM: conv(taps)+bias [+relu+LN] +mask [+final proj] ----
// R5-proven conventions; adds register double-buffered operand prefetch and an
// optional fused 4x192 output projection (fin mode: no bf16 store, writes fout).
#define LOADOPS(IT, AH0, AL0, AH1, AL1, BH, BL) do {                              \
    int kt_ = (IT) / 6, s_ = (IT) - kt_ * 6;                                      \
    const ushort_t* arow_ = inb + (long)(trow + kt_ - pad) * ROWP + s_ * 32 + kg; \
    AH0 = *(const short8*)(arow_);                                                \
    AL0 = *(const short8*)(arow_ + H);                                            \
    AH1 = *(const short8*)(arow_ + 16 * ROWP);                                    \
    AL1 = *(const short8*)(arow_ + 16 * ROWP + H);                                \
    const ushort_t* wb_ = wt + ((size_t)((kt_ * 6 + s_) * 12 + nhalf * 6) << 9)   \
                        + (lane << 3);                                            \
    _Pragma("unroll") for (int n_ = 0; n_ < 6; ++n_) {                            \
        BH[n_] = *(const short8*)(wb_ + (n_ << 9));                               \
        BL[n_] = *(const short8*)(wb_ + (n_ << 9) + ntotw); }                     \
} while (0)

#define DOMFMA(AH0, AL0, AH1, AL1, BH, BL) do {                                             \
    _Pragma("unroll") for (int n_ = 0; n_ < 6; ++n_) {                                      \
        acc[0][n_] = __builtin_amdgcn_mfma_f32_16x16x32_bf16(AH0, BH[n_], acc[0][n_], 0,0,0); \
        acc[0][n_] = __builtin_amdgcn_mfma_f32_16x16x32_bf16(AL0, BH[n_], acc[0][n_], 0,0,0); \
        acc[0][n_] = __builtin_amdgcn_mfma_f32_16x16x32_bf16(AH0, BL[n_], acc[0][n_], 0,0,0); \
        acc[1][n_] = __builtin_amdgcn_mfma_f32_16x16x32_bf16(AH1, BH[n_], acc[1][n_], 0,0,0); \
        acc[1][n_] = __builtin_amdgcn_mfma_f32_16x16x32_bf16(AL1, BH[n_], acc[1][n_], 0,0,0); \
        acc[1][n_] = __builtin_amdgcn_mfma_f32_16x16x32_bf16(AH1, BL[n_], acc[1][n_], 0,0,0); } \
} while (0)

__global__ __launch_bounds__(256) void gemm_fused_kernel(
    const ushort_t* __restrict__ in, int in_rows,
    const ushort_t* __restrict__ wt,
    const float* __restrict__ bias,
    const float* __restrict__ mask,
    const float* __restrict__ g, const float* __restrict__ beta,
    ushort_t* __restrict__ out,
    const float* __restrict__ lw, const float* __restrict__ lb,
    float* __restrict__ fout,
    int taps, int do_ln, int nmask, int fin)
{
    int b  = blockIdx.y;
    int t0 = blockIdx.x * 64;
    int tid = threadIdx.x;
    int lane = tid & 63;
    int wv = tid >> 6;
    int mhalf = wv & 1;
    int nhalf = wv >> 1;

    __shared__ float ep[64][193];
    __shared__ float g_s[H], b_s[H], m_s[64], mstat[64], rstat[64];
    if (tid < H) { g_s[tid] = do_ln ? g[tid] : 1.f; b_s[tid] = do_ln ? beta[tid] : 0.f; }
    if (tid < 64) m_s[tid] = mask[b * N_PH + t0 + tid];

    // zero halo rows (t=-1 and t=N_PH), both planes (skip in fin mode: no store)
    short8 z8 = {0, 0, 0, 0, 0, 0, 0, 0};
    if (!fin) {
        if (t0 == 0 && tid < ROWP / 8)
            *(short8*)(out + (size_t)b * PROWS * ROWP + tid * 8) = z8;
        if (t0 == N_PH - 64 && tid < ROWP / 8)
            *(short8*)(out + ((size_t)b * PROWS + N_PH + 1) * ROWP + tid * 8) = z8;
    }

    int m  = lane & 15;                 // A time-row / B channel / D col
    int kg = (lane >> 4) << 3;          // k offset within 32-step: 0,8,16,24
    int ntotw = taps * 36864;           // hi-plane size; lo at +ntotw
    int pad = taps >> 1;

    const ushort_t* inb = in + (size_t)b * in_rows * ROWP;
    int trow = t0 + mhalf * 32 + m;     // +16 for second A-frag

    f32x4 acc[2][6];
#pragma unroll
    for (int ntl = 0; ntl < 6; ++ntl) {
        float bb = bias[(nhalf * 6 + ntl) * 16 + m];
        acc[0][ntl] = (f32x4){bb, bb, bb, bb};
        acc[1][ntl] = (f32x4){bb, bb, bb, bb};
    }

    // K-loop with register double-buffered prefetch (iters = 6 or 18, even)
    short8 pah0, pal0, pah1, pal1, pbh[6], pbl[6];
    short8 qah0, qal0, qah1, qal1, qbh[6], qbl[6];
    int iters = taps * 6;
    LOADOPS(0, pah0, pal0, pah1, pal1, pbh, pbl);
#pragma unroll 1
    for (int it = 0; it < iters; it += 2) {
        LOADOPS(it + 1, qah0, qal0, qah1, qal1, qbh, qbl);
        DOMFMA(pah0, pal0, pah1, pal1, pbh, pbl);
        if (it + 2 < iters) LOADOPS(it + 2, pah0, pal0, pah1, pal1, pbh, pbl);
        DOMFMA(qah0, qal0, qah1, qal1, qbh, qbl);
    }

    __syncthreads();   // covers g_s/b_s/m_s staging

    // write pre-LN (or final-masked) values to LDS, C/D layout -> [time][channel]
    int rbase = (lane >> 4) << 2;
#pragma unroll
    for (int mh = 0; mh < 2; ++mh) {
#pragma unroll
        for (int ntl = 0; ntl < 6; ++ntl) {
            int o = (nhalf * 6 + ntl) * 16 + m;
#pragma unroll
            for (int r = 0; r < 4; ++r) {
                int t_loc = mhalf * 32 + mh * 16 + rbase + r;
                float mm = m_s[t_loc];
                float v = acc[mh][ntl][r];
                if (do_ln) {
                    v = fmaxf(v * mm, 0.f) * mm;     // relu(conv*mask)*mask -> LN input
                } else {
                    for (int q = 0; q < nmask; ++q) v *= mm;
                }
                ep[t_loc][o] = v;
            }
        }
    }
    __syncthreads();

    // LN stats: one thread per time row (scalar reads -- ep pitch 193 not 16B aligned)
    if (do_ln && tid < 64) {
        float s = 0.f, ss = 0.f;
        for (int c = 0; c < H; ++c) {
            float v = ep[tid][c];
            s += v;
            ss += v * v;
        }
        float mean = s * (1.f / (float)H);
        mstat[tid] = mean;
        rstat[tid] = rsqrtf(ss * (1.f / (float)H) - mean * mean + 1e-5f);
    }
    __syncthreads();

    int row = tid >> 2;
    int q = tid & 3;
    if (fin) {
        // fused final projection: p[o] = (sum_c lw[o][c] * (ln(c)*mk) + lb[o]) * mk
        float mean = mstat[row], rstd = rstat[row], mk = m_s[row];
        float a0 = 0.f, a1 = 0.f, a2 = 0.f, a3 = 0.f;
#pragma unroll 1
        for (int c = q * 48; c < q * 48 + 48; ++c) {
            float y = ((ep[row][c] - mean) * rstd * g_s[c] + b_s[c]) * mk;
            a0 += lw[0 * H + c] * y;
            a1 += lw[1 * H + c] * y;
            a2 += lw[2 * H + c] * y;
            a3 += lw[3 * H + c] * y;
        }
        a0 += __shfl_xor(a0, 1); a0 += __shfl_xor(a0, 2);
        a1 += __shfl_xor(a1, 1); a1 += __shfl_xor(a1, 2);
        a2 += __shfl_xor(a2, 1); a2 += __shfl_xor(a2, 2);
        a3 += __shfl_xor(a3, 1); a3 += __shfl_xor(a3, 2);
        if (q == 0) {
            int t = t0 + row;
            float* ob = fout + (size_t)b * OUT * N_PH + t;
            ob[0 * N_PH] = (a0 + lb[0]) * mk;
            ob[1 * N_PH] = (a1 + lb[1]) * mk;
            ob[2 * N_PH] = (a2 + lb[2]) * mk;
            ob[3 * N_PH] = (a3 + lb[3]) * mk;
        }
        return;
    }

    // store: 4 threads per row, 48 channels each, split bf16
    float mean = 0.f, rstd = 1.f, mfac = 1.f;
    if (do_ln) {
        mean = mstat[row];
        rstd = rstat[row];
        float mk = m_s[row];
        mfac = (nmask == 2) ? mk * mk : mk;
    }
    ushort_t* orow = out + ((size_t)b * PROWS + t0 + row + 1) * ROWP + q * 48;
#pragma unroll
    for (int i0 = 0; i0 < 48; i0 += 8) {
        ushort_t th[8], tl[8];
#pragma unroll
        for (int k2 = 0; k2 < 8; ++k2) {
            int c = q * 48 + i0 + k2;
            float v = ep[row][c];
            float y = do_ln ? ((v - mean) * rstd * g_s[c] + b_s[c]) * mfac : v;
            split_bf(y, th[k2], tl[k2]);
        }
        *(short8*)(orow + i0) = *(short8*)th;
        *(short8*)(orow + H + i0) = *(short8*)tl;
    }
}

extern "C" void kernel_launch(void* const* d_in, const int* in_sizes, int n_in,
                              void* d_out, int out_size, void* d_ws, size_t ws_size,
                              hipStream_t stream) {
    const float* x      = (const float*)d_in[0];
    const float* x_mask = (const float*)d_in[1];
    const int*   w      = (const int*)d_in[2];
    const float* pre_w  = (const float*)d_in[3];
    const float* pre_b  = (const float*)d_in[4];
    const float* conv0_w = (const float*)d_in[5];
    const float* conv0_b = (const float*)d_in[6];
    const float* ln0_g   = (const float*)d_in[7];
    const float* ln0_b   = (const float*)d_in[8];
    const float* conv1_w = (const float*)d_in[9];
    const float* conv1_b = (const float*)d_in[10];
    const float* ln1_g   = (const float*)d_in[11];
    const float* ln1_b   = (const float*)d_in[12];
    const float* lin_w   = (const float*)d_in[13];
    const float* lin_b   = (const float*)d_in[14];
    float* out = (float*)d_out;

    // workspace layout
    char* ws = (char*)d_ws;
    size_t off = 0;
    float* spec = (float*)(ws + off);       off += (size_t)B * C_IN * N_PH * sizeof(float);
    ushort_t* bufA = (ushort_t*)(ws + off); off += (size_t)B * PROWS * ROWP * sizeof(ushort_t);
    ushort_t* bufB = (ushort_t*)(ws + off); off += (size_t)B * PROWS * ROWP * sizeof(ushort_t);
    ushort_t* wpre = (ushort_t*)(ws + off); off += (size_t)2 * 36864 * sizeof(ushort_t);
    ushort_t* w0t  = (ushort_t*)(ws + off); off += (size_t)2 * 110592 * sizeof(ushort_t);
    ushort_t* w1t  = (ushort_t*)(ws + off); off += (size_t)2 * 110592 * sizeof(ushort_t);
    // specT aliases bufB: consumed by pregemm before conv0 first writes bufB
    ushort_t* specT = bufB;

    // all weight fragments in one dispatch
    wfrag_all_kernel<<<(36864 + 2 * 110592 + 255) / 256, 256, 0, stream>>>(
        pre_w, conv0_w, conv1_w, wpre, w0t, w1t);

    // segment mean (with inline duration scan) + transpose to time-major split bf16
    segmean_kernel<<<B * C_IN, 256, 0, stream>>>(x, w, spec);
    dim3 gt(N_PH / 32, (C_IN / 32) * B);
    transpose_spec_kernel<<<gt, 256, 0, stream>>>(spec, specT);

    dim3 gg(N_PH / 64, B);
    // pre linear: specT (pitch N_PH rows) -> bufA (mask applied for conv0 input)
    gemm_fused_kernel<<<gg, 256, 0, stream>>>(specT, N_PH, wpre, pre_b, x_mask,
                                              ln0_g, ln0_b, bufA,
                                              nullptr, nullptr, nullptr, 1, 0, 1, 0);
    // block 0: bufA -> bufB  (out = ln0*mask, + conv1's leading mask)
    gemm_fused_kernel<<<gg, 256, 0, stream>>>(bufA + ROWP, PROWS, w0t, conv0_b, x_mask,
                                              ln0_g, ln0_b, bufB,
                                              nullptr, nullptr, nullptr, 3, 1, 2, 0);
    // block 1 + fused final projection: bufB -> out
    gemm_fused_kernel<<<gg, 256, 0, stream>>>(bufB + ROWP, PROWS, w1t, conv1_b, x_mask,
                                              ln1_g, ln1_b, bufA,
                                              lin_w, lin_b, out, 3, 1, 1, 1);
}